// Round 1
// baseline (173.971 us; speedup 1.0000x reference)
//
#include <hip/hip_runtime.h>
#include <math.h>

#define BS_     64
#define NUM_KP_ 17
#define A_      8400
#define GRID_   80          // IMAGE_SIZE / STRIDES[0] = 640/8
#define NCH_    (3 * NUM_KP_)   // 51
#define NCONF_  ((float)(BS_ * NUM_KP_ * A_))  // 9139200

// One block per (batch, keypoint) conf row. Reduces clamp(log1p(-c)) over the
// row; thread 0 additionally handles the gather terms for this (b,k).
__global__ __launch_bounds__(256) void yolo_kploss_main(
    const float* __restrict__ out,   // (BS, 51, 8400)
    const float* __restrict__ gt,    // (BS, 17, 2)
    const int*   __restrict__ visv,  // (BS, 17)
    float*       __restrict__ ws)    // ws[0] = conf log-sum, ws[1] = xy sq-err sum
{
    const int row = blockIdx.x;              // 0 .. 1087
    const int b   = row / NUM_KP_;
    const int k   = row - b * NUM_KP_;
    const int tid = threadIdx.x;

    const float* conf_row = out + ((size_t)b * NCH_ + 3 * k + 2) * A_;

    float conf_part = 0.0f;

    // A_ = 8400 = 2100 float4, contiguous & 16B-aligned (row offset multiple of 8400 floats... 8400*4B=33600B, 16B-aligned)
    const float4* c4 = (const float4*)conf_row;
    #pragma unroll 2
    for (int i = tid; i < A_ / 4; i += 256) {
        float4 v = c4[i];
        conf_part += fmaxf(log1pf(-v.x), -100.0f);
        conf_part += fmaxf(log1pf(-v.y), -100.0f);
        conf_part += fmaxf(log1pf(-v.z), -100.0f);
        conf_part += fmaxf(log1pf(-v.w), -100.0f);
    }

    float xy_part = 0.0f;
    if (tid == 0) {
        const float gx = gt[(b * NUM_KP_ + k) * 2 + 0];
        const float gy = gt[(b * NUM_KP_ + k) * 2 + 1];
        const int   vv = visv[b * NUM_KP_ + k];
        if (vv == 1) {
            const int bx  = (int)floorf(gx * 0.125f);
            const int by  = (int)floorf(gy * 0.125f);
            const int idx = by * GRID_ + bx;        // < 6400 < 8400
            const float xg = out[((size_t)b * NCH_ + 3 * k + 0) * A_ + idx];
            const float yg = out[((size_t)b * NCH_ + 3 * k + 1) * A_ + idx];
            const float c  = conf_row[idx];
            xy_part = (xg - gx) * (xg - gx) + (yg - gy) * (yg - gy);
            const float logp   = fmaxf(logf(c),     -100.0f);
            const float log1mp = fmaxf(log1pf(-c),  -100.0f);
            conf_part += (logp - log1mp);   // masked position: logp replaces log1mp
        }
    }

    // Block reduce conf_part: wave64 shuffle, then LDS across the 4 waves.
    #pragma unroll
    for (int off = 32; off > 0; off >>= 1)
        conf_part += __shfl_down(conf_part, off, 64);

    __shared__ float s[4];
    const int wave = tid >> 6;
    const int lane = tid & 63;
    if (lane == 0) s[wave] = conf_part;
    __syncthreads();

    if (tid == 0) {
        const float total = s[0] + s[1] + s[2] + s[3];
        atomicAdd(&ws[0], total);
        if (xy_part != 0.0f) atomicAdd(&ws[1], xy_part);
    }
}

__global__ void yolo_kploss_final(const float* __restrict__ ws,
                                  float* __restrict__ out)
{
    out[0] = -ws[0] / NCONF_ + ws[1] / (float)BS_;
}

extern "C" void kernel_launch(void* const* d_in, const int* in_sizes, int n_in,
                              void* d_out, int out_size, void* d_ws, size_t ws_size,
                              hipStream_t stream) {
    const float* out_t = (const float*)d_in[0];   // (64, 51, 8400) fp32
    // d_in[1] = target, unused by the reference math
    const float* gt    = (const float*)d_in[2];   // (64, 17, 2) fp32
    const int*   vis   = (const int*)d_in[3];     // (64, 17) int32

    float* ws = (float*)d_ws;
    hipMemsetAsync(ws, 0, 2 * sizeof(float), stream);

    yolo_kploss_main<<<BS_ * NUM_KP_, 256, 0, stream>>>(out_t, gt, vis, ws);
    yolo_kploss_final<<<1, 1, 0, stream>>>(ws, (float*)d_out);
}